// Round 1
// baseline (509.737 us; speedup 1.0000x reference)
//
#include <hip/hip_runtime.h>
#include <hip/hip_fp16.h>
#include <math.h>

// A3TGCN reduced form (H0 == 0 => r-branch dead, GRU collapses):
//   agg[n,p] = dinv[n] * ( sum_{e: dst=n} xs[src[e],p] + xs[n,p] ),  xs = dinv .* x
//   z = sigmoid(agg*az[c]+cz[c]); h = tanh(agg*ah[c]+ch[c])
//   out[n,:] = (sum_p probs[p]*(1-z)*h) @ out_w + out_b
//
// Round 8: replace {counting sort (k_binB) + sorted gather (k_aggF)} with a
// single fused pass (k_agg) that reads binned edges once and accumulates
// directly into a per-bucket LDS accumulator via ds_add_f32 (sum is
// order-independent; the sort only existed to make runs contiguous).
// Accumulator stride 13 (coprime with 32 banks; stride 12 hits only 8 banks).
// Degrees now come from a global atomicAdd folded into k_binA's edge read
// (was: nofs diffs from the sort), and k_binA register-stages src/dst so the
// edge list is read once instead of twice. nodesorted/nofs buffers removed.

#define PERIODS 12
#define BSZ     256              // nodes per bucket (2^BSH)
#define BSH     8
#define STRIDE  9216             // bucket capacity: mean 8192 + 11 sigma
#define SRCBITS 17               // N = 100000 < 2^17
#define SMASK   ((1 << SRCBITS) - 1)
#define CH      4096             // edges per k_binA block
#define ACCS    13               // LDS accumulator stride (bank-conflict pad)

struct Consts {
    float az[4], cz[4], ah[4], ch[4], probs[PERIODS];
};

// ---------------- fp8 e4m3 helpers (builtin fast path + manual fallback) ----
typedef float vf2 __attribute__((ext_vector_type(2)));

__device__ __forceinline__ float dec1_manual(unsigned b) {
    unsigned e = (b >> 3) & 15u, m = b & 7u;
    float v = e ? __uint_as_float(((e + 120u) << 23) | (m << 20))
                : (float)m * 0.001953125f;          // 2^-9 subnormal step
    return (b & 0x80u) ? -v : v;
}

__device__ __forceinline__ void dec4(unsigned u, float* o) {
#if __has_builtin(__builtin_amdgcn_cvt_pk_f32_fp8)
    vf2 lo = __builtin_amdgcn_cvt_pk_f32_fp8((int)u, false);
    vf2 hi = __builtin_amdgcn_cvt_pk_f32_fp8((int)u, true);
    o[0] = lo.x; o[1] = lo.y; o[2] = hi.x; o[3] = hi.y;
#else
    o[0] = dec1_manual(u & 255u);
    o[1] = dec1_manual((u >> 8) & 255u);
    o[2] = dec1_manual((u >> 16) & 255u);
    o[3] = dec1_manual(u >> 24);
#endif
}

__device__ __forceinline__ unsigned enc1_manual(float x) {
    unsigned s = (__float_as_uint(x) >> 24) & 0x80u;
    float a = fabsf(x);
    if (!(a > 0.f)) return s;
    a = fminf(a, 448.f);
    int eb = (int)(__float_as_uint(a) >> 23) - 127;
    int e = eb < -6 ? -6 : eb;
    float q = rintf(a * exp2f((float)(3 - e)));
    if (q >= 16.f) { e++; q = rintf(a * exp2f((float)(3 - e))); }
    if (e > 8) return s | 0x7Eu;                    // clamp to 448
    int m = (int)q;
    unsigned ee, mm;
    if (m >= 8) { ee = (unsigned)(e + 7); mm = (unsigned)(m - 8); }
    else        { ee = 0u; mm = (unsigned)m; }      // subnormal (e == -6)
    return s | (ee << 3) | mm;
}

__device__ __forceinline__ unsigned pk4(float a, float b, float c, float d) {
#if __has_builtin(__builtin_amdgcn_cvt_pk_fp8_f32)
    int v = __builtin_amdgcn_cvt_pk_fp8_f32(a, b, 0, false);
    v = __builtin_amdgcn_cvt_pk_fp8_f32(c, d, v, true);
    return (unsigned)v;
#else
    return enc1_manual(a) | (enc1_manual(b) << 8) |
           (enc1_manual(c) << 16) | (enc1_manual(d) << 24);
#endif
}

// ---------------------------------------------------------------------------

// Grid-wide: zero deg[] + gcur[]; block 0 / thread 0 folds the constants.
__global__ __launch_bounds__(512) void k_setup(const float* conv_z_w, const float* conv_z_b,
                        const float* lin_z_w, const float* lin_z_b,
                        const float* conv_h_w, const float* conv_h_b,
                        const float* lin_h_w, const float* lin_h_b,
                        const float* att, Consts* C, int* gcur, int* deg,
                        int NB, int N)
{
    int g = blockIdx.x * 512 + threadIdx.x;
    int gs = gridDim.x * 512;
    for (int i = g; i < N; i += gs) deg[i] = 0;
    if (blockIdx.x == 0) {
        int t = threadIdx.x;
        for (int i = t; i < NB; i += 512) gcur[i] = 0;
        if (t == 0) {
            for (int c = 0; c < 4; ++c) {
                float az = 0.f, cz = 0.f, ah = 0.f, ch = 0.f;
                for (int k = 0; k < 4; ++k) {
                    az += conv_z_w[k] * lin_z_w[k * 4 + c];
                    cz += conv_z_b[k] * lin_z_w[k * 4 + c];
                    ah += conv_h_w[k] * lin_h_w[k * 4 + c];
                    ch += conv_h_b[k] * lin_h_w[k * 4 + c];
                }
                C->az[c] = az; C->cz[c] = cz + lin_z_b[c];
                C->ah[c] = ah; C->ch[c] = ch + lin_h_b[c];
            }
            float m = att[0];
            for (int p = 1; p < PERIODS; ++p) m = fmaxf(m, att[p]);
            float e[PERIODS]; float s = 0.f;
            for (int p = 0; p < PERIODS; ++p) { e[p] = expf(att[p] - m); s += e[p]; }
            for (int p = 0; p < PERIODS; ++p) C->probs[p] = e[p] / s;
        }
    }
}

// Pass 1: bin edges by dst bucket; register-stage src/dst (edge list read
// once); fold per-dst-node degree histogram (global atomics, L2-resident).
__global__ __launch_bounds__(512) void k_binA(const int* __restrict__ ei,
                                              int* __restrict__ gcur,
                                              int* __restrict__ deg,
                                              int* __restrict__ binned, int E) {
    __shared__ int hist[512];
    __shared__ int scn[512];
    __shared__ int gdel[512];
    __shared__ int sv[CH];
    __shared__ int sa[CH];
    int t = threadIdx.x;
    hist[t] = 0;
    __syncthreads();
    int base = blockIdx.x * CH;
    int lim = min(E - base, CH);
    int rs[CH / 512], rd[CH / 512];
    #pragma unroll
    for (int k = 0; k < CH / 512; ++k) {
        int i = t + k * 512;
        if (i < lim) {
            rs[k] = ei[base + i];
            rd[k] = ei[E + base + i];
            atomicAdd(&hist[rd[k] >> BSH], 1);
            atomicAdd(&deg[rd[k]], 1);
        }
    }
    __syncthreads();
    int v = hist[t];
    scn[t] = v;
    __syncthreads();
    for (int off = 1; off < 512; off <<= 1) {
        int tmp = (t >= off) ? scn[t - off] : 0;
        __syncthreads();
        scn[t] += tmp;
        __syncthreads();
    }
    int excl = scn[t] - v;
    int g = (v > 0) ? atomicAdd(&gcur[t], v) : 0;
    gdel[t] = t * STRIDE + g - excl;
    hist[t] = excl;
    __syncthreads();
    #pragma unroll
    for (int k = 0; k < CH / 512; ++k) {
        int i = t + k * 512;
        if (i < lim) {
            int s = rs[k];
            int d = rd[k];
            int b = d >> BSH;
            int pos = atomicAdd(&hist[b], 1);
            sv[pos] = ((d & (BSZ - 1)) << SRCBITS) | s;
            sa[pos] = gdel[b] + pos;
        }
    }
    __syncthreads();
    for (int j = t; j < lim; j += 512)
        binned[sa[j]] = sv[j];
}

// Per node: degree -> dinv + fp8 xs row (16 B).
__global__ void k_prep(const int* __restrict__ deg,
                       const float* __restrict__ x, float* __restrict__ dinv,
                       uint4* __restrict__ xs8, int N) {
    int n = blockIdx.x * blockDim.x + threadIdx.x;
    if (n >= N) return;
    float di = rsqrtf((float)deg[n] + 1.0f);   // +1 = self loop
    dinv[n] = di;
    const float4* xv = (const float4*)(x + (size_t)n * PERIODS);
    float4 v0 = xv[0], v1 = xv[1], v2 = xv[2];
    uint4 r;
    r.x = pk4(v0.x * di, v0.y * di, v0.z * di, v0.w * di);
    r.y = pk4(v1.x * di, v1.y * di, v1.z * di, v1.w * di);
    r.z = pk4(v2.x * di, v2.y * di, v2.z * di, v2.w * di);
    r.w = 0;
    xs8[n] = r;
}

__device__ __forceinline__ void scat(float* acc, int d, uint4 r) {
    float f[PERIODS];
    dec4(r.x, f + 0); dec4(r.y, f + 4); dec4(r.z, f + 8);
    int base = d * ACCS;
    #pragma unroll
    for (int k = 0; k < PERIODS; ++k) atomicAdd(&acc[base + k], f[k]);
}

// Pass 2 (fused): read bucket's binned edges once; gather fp8 src row;
// ds_add_f32 into per-bucket accumulator; threads 0..255 run the epilogue.
__global__ __launch_bounds__(512) void k_agg(const int* __restrict__ binned,
                                             const int* __restrict__ gcur,
                                             const float* __restrict__ dinv,
                                             const uint4* __restrict__ xs8,
                                             const Consts* __restrict__ C,
                                             const float* __restrict__ out_w,
                                             const float* __restrict__ out_b,
                                             float* __restrict__ out, int N) {
    __shared__ float acc[BSZ * ACCS];
    int b = blockIdx.x, t = threadIdx.x;
    for (int i = t; i < BSZ * ACCS; i += 512) acc[i] = 0.f;
    __syncthreads();
    int cnt = gcur[b];
    const int* bb = binned + b * STRIDE;
    int i = t;
    for (; i + 1536 < cnt; i += 2048) {      // x4: 4 col loads + 4 gathers in flight
        int p0 = bb[i];
        int p1 = bb[i + 512];
        int p2 = bb[i + 1024];
        int p3 = bb[i + 1536];
        uint4 r0 = xs8[p0 & SMASK];
        uint4 r1 = xs8[p1 & SMASK];
        uint4 r2 = xs8[p2 & SMASK];
        uint4 r3 = xs8[p3 & SMASK];
        scat(acc, p0 >> SRCBITS, r0);
        scat(acc, p1 >> SRCBITS, r1);
        scat(acc, p2 >> SRCBITS, r2);
        scat(acc, p3 >> SRCBITS, r3);
    }
    for (; i < cnt; i += 512) {
        int pv = bb[i];
        uint4 r = xs8[pv & SMASK];
        scat(acc, pv >> SRCBITS, r);
    }
    __syncthreads();

    if (t >= BSZ) return;
    int n = (b << BSH) + t;
    if (n >= N) return;

    float a[PERIODS];
    {   // self term (di-scaled fp8 row) + accumulated neighbors
        float f[PERIODS];
        uint4 r = xs8[n];
        dec4(r.x, f + 0); dec4(r.y, f + 4); dec4(r.z, f + 8);
        #pragma unroll
        for (int k = 0; k < PERIODS; ++k) a[k] = acc[t * ACCS + k] + f[k];
    }

    float di = dinv[n];
    float hacc[4] = {0.f, 0.f, 0.f, 0.f};
    #pragma unroll
    for (int p = 0; p < PERIODS; ++p) {
        float ap = di * a[p];
        float pr = C->probs[p];
        #pragma unroll
        for (int c = 0; c < 4; ++c) {
            float zz = 1.f / (1.f + __expf(-(ap * C->az[c] + C->cz[c])));
            float hh = tanhf(ap * C->ah[c] + C->ch[c]);
            hacc[c] += pr * (1.f - zz) * hh;
        }
    }
    float o[PERIODS];
    #pragma unroll
    for (int f = 0; f < PERIODS; ++f) {
        float v = out_b[f];
        #pragma unroll
        for (int c = 0; c < 4; ++c) v += hacc[c] * out_w[c * PERIODS + f];
        o[f] = v;
    }
    float4* ov = (float4*)(out + (size_t)n * PERIODS);
    ov[0] = make_float4(o[0], o[1], o[2],  o[3]);
    ov[1] = make_float4(o[4], o[5], o[6],  o[7]);
    ov[2] = make_float4(o[8], o[9], o[10], o[11]);
}

extern "C" void kernel_launch(void* const* d_in, const int* in_sizes, int n_in,
                              void* d_out, int out_size, void* d_ws, size_t ws_size,
                              hipStream_t stream) {
    const float* x        = (const float*)d_in[0];
    const int*   ei       = (const int*)d_in[1];
    const float* conv_z_w = (const float*)d_in[2];
    const float* conv_z_b = (const float*)d_in[3];
    const float* lin_z_w  = (const float*)d_in[4];
    const float* lin_z_b  = (const float*)d_in[5];
    const float* conv_h_w = (const float*)d_in[10];
    const float* conv_h_b = (const float*)d_in[11];
    const float* lin_h_w  = (const float*)d_in[12];
    const float* lin_h_b  = (const float*)d_in[13];
    const float* att      = (const float*)d_in[14];
    const float* out_w    = (const float*)d_in[15];
    const float* out_b    = (const float*)d_in[16];
    float* out = (float*)d_out;

    const int N  = in_sizes[0] / PERIODS;
    const int E  = in_sizes[1] / 2;
    const int NB = (N + BSZ - 1) / BSZ;          // 391 buckets
    const int gA = (E + CH - 1) / CH;            // binning blocks

    // workspace layout (256B-aligned regions); total ~21 MB
    char* ws = (char*)d_ws;
    size_t off = 0;
    Consts* consts = (Consts*)(ws + off);  off += (sizeof(Consts) + 255) & ~255ull;
    int*    gcur   = (int*)(ws + off);     off += ((size_t)NB * 4 + 255) & ~255ull;
    int*    deg    = (int*)(ws + off);     off += ((size_t)N * 4 + 255) & ~255ull;
    float*  dinv   = (float*)(ws + off);   off += ((size_t)N * 4 + 255) & ~255ull;
    uint4*  xs8    = (uint4*)(ws + off);   off += ((size_t)(N + 256) * 16 + 255) & ~255ull;
    int*    binned = (int*)(ws + off);     off += ((size_t)NB * STRIDE * 4 + 255) & ~255ull;
    (void)ws_size; (void)n_in; (void)out_size;

    k_setup<<<128, 512, 0, stream>>>(conv_z_w, conv_z_b, lin_z_w, lin_z_b,
                                     conv_h_w, conv_h_b, lin_h_w, lin_h_b, att,
                                     consts, gcur, deg, NB, N);
    k_binA<<<gA, 512, 0, stream>>>(ei, gcur, deg, binned, E);
    k_prep<<<(N + 255) / 256, 256, 0, stream>>>(deg, x, dinv, xs8, N);
    k_agg<<<NB, 512, 0, stream>>>(binned, gcur, dinv, xs8, consts,
                                  out_w, out_b, out, N);
}

// Round 2
// 278.874 us; speedup vs baseline: 1.8278x; 1.8278x over previous
//
#include <hip/hip_runtime.h>
#include <hip/hip_fp16.h>
#include <math.h>

// A3TGCN reduced form (H0 == 0 => r-branch dead, GRU collapses):
//   agg[n,p] = dinv[n] * ( sum_{e: dst=n} xs[src[e],p] + xs[n,p] ),  xs = dinv .* x
//   z = sigmoid(agg*az[c]+cz[c]); h = tanh(agg*ah[c]+ch[c])
//   out[n,:] = (sum_p probs[p]*(1-z)*h) @ out_w + out_b
//
// Round 9: round 8's fused k_agg was 263 us because atomicAdd(float*) on LDS
// compiles to a CAS loop without -munsafe-fp-atomics (VALUBusy 1.9% = pure
// lgkm stall). Fix: accumulate in INTEGER units of 2^-9 (every fp8 e4m3 value
// is an exact multiple of 2^-9, <= 448*512 = 229376 units; degree ~32 keeps
// sums << 2^31). atomicAdd(int*) emits native ds_add_u32. Exact + deterministic.

#define PERIODS 12
#define BSZ     256              // nodes per bucket (2^BSH)
#define BSH     8
#define STRIDE  9216             // bucket capacity: mean 8192 + 11 sigma
#define SRCBITS 17               // N = 100000 < 2^17
#define SMASK   ((1 << SRCBITS) - 1)
#define CH      4096             // edges per k_binA block
#define ACCS    13               // LDS accumulator stride (bank-conflict pad)

struct Consts {
    float az[4], cz[4], ah[4], ch[4], probs[PERIODS];
};

// ---------------- fp8 e4m3 helpers (builtin fast path + manual fallback) ----
typedef float vf2 __attribute__((ext_vector_type(2)));

__device__ __forceinline__ float dec1_manual(unsigned b) {
    unsigned e = (b >> 3) & 15u, m = b & 7u;
    float v = e ? __uint_as_float(((e + 120u) << 23) | (m << 20))
                : (float)m * 0.001953125f;          // 2^-9 subnormal step
    return (b & 0x80u) ? -v : v;
}

__device__ __forceinline__ void dec4(unsigned u, float* o) {
#if __has_builtin(__builtin_amdgcn_cvt_pk_f32_fp8)
    vf2 lo = __builtin_amdgcn_cvt_pk_f32_fp8((int)u, false);
    vf2 hi = __builtin_amdgcn_cvt_pk_f32_fp8((int)u, true);
    o[0] = lo.x; o[1] = lo.y; o[2] = hi.x; o[3] = hi.y;
#else
    o[0] = dec1_manual(u & 255u);
    o[1] = dec1_manual((u >> 8) & 255u);
    o[2] = dec1_manual((u >> 16) & 255u);
    o[3] = dec1_manual(u >> 24);
#endif
}

__device__ __forceinline__ unsigned enc1_manual(float x) {
    unsigned s = (__float_as_uint(x) >> 24) & 0x80u;
    float a = fabsf(x);
    if (!(a > 0.f)) return s;
    a = fminf(a, 448.f);
    int eb = (int)(__float_as_uint(a) >> 23) - 127;
    int e = eb < -6 ? -6 : eb;
    float q = rintf(a * exp2f((float)(3 - e)));
    if (q >= 16.f) { e++; q = rintf(a * exp2f((float)(3 - e))); }
    if (e > 8) return s | 0x7Eu;                    // clamp to 448
    int m = (int)q;
    unsigned ee, mm;
    if (m >= 8) { ee = (unsigned)(e + 7); mm = (unsigned)(m - 8); }
    else        { ee = 0u; mm = (unsigned)m; }      // subnormal (e == -6)
    return s | (ee << 3) | mm;
}

__device__ __forceinline__ unsigned pk4(float a, float b, float c, float d) {
#if __has_builtin(__builtin_amdgcn_cvt_pk_fp8_f32)
    int v = __builtin_amdgcn_cvt_pk_fp8_f32(a, b, 0, false);
    v = __builtin_amdgcn_cvt_pk_fp8_f32(c, d, v, true);
    return (unsigned)v;
#else
    return enc1_manual(a) | (enc1_manual(b) << 8) |
           (enc1_manual(c) << 16) | (enc1_manual(d) << 24);
#endif
}

// ---------------------------------------------------------------------------

// Grid-wide: zero deg[] + gcur[]; block 0 / thread 0 folds the constants.
__global__ __launch_bounds__(512) void k_setup(const float* conv_z_w, const float* conv_z_b,
                        const float* lin_z_w, const float* lin_z_b,
                        const float* conv_h_w, const float* conv_h_b,
                        const float* lin_h_w, const float* lin_h_b,
                        const float* att, Consts* C, int* gcur, int* deg,
                        int NB, int N)
{
    int g = blockIdx.x * 512 + threadIdx.x;
    int gs = gridDim.x * 512;
    for (int i = g; i < N; i += gs) deg[i] = 0;
    if (blockIdx.x == 0) {
        int t = threadIdx.x;
        for (int i = t; i < NB; i += 512) gcur[i] = 0;
        if (t == 0) {
            for (int c = 0; c < 4; ++c) {
                float az = 0.f, cz = 0.f, ah = 0.f, ch = 0.f;
                for (int k = 0; k < 4; ++k) {
                    az += conv_z_w[k] * lin_z_w[k * 4 + c];
                    cz += conv_z_b[k] * lin_z_w[k * 4 + c];
                    ah += conv_h_w[k] * lin_h_w[k * 4 + c];
                    ch += conv_h_b[k] * lin_h_w[k * 4 + c];
                }
                C->az[c] = az; C->cz[c] = cz + lin_z_b[c];
                C->ah[c] = ah; C->ch[c] = ch + lin_h_b[c];
            }
            float m = att[0];
            for (int p = 1; p < PERIODS; ++p) m = fmaxf(m, att[p]);
            float e[PERIODS]; float s = 0.f;
            for (int p = 0; p < PERIODS; ++p) { e[p] = expf(att[p] - m); s += e[p]; }
            for (int p = 0; p < PERIODS; ++p) C->probs[p] = e[p] / s;
        }
    }
}

// Pass 1: bin edges by dst bucket; register-stage src/dst (edge list read
// once); fold per-dst-node degree histogram (global atomics, L2-resident).
__global__ __launch_bounds__(512) void k_binA(const int* __restrict__ ei,
                                              int* __restrict__ gcur,
                                              int* __restrict__ deg,
                                              int* __restrict__ binned, int E) {
    __shared__ int hist[512];
    __shared__ int scn[512];
    __shared__ int gdel[512];
    __shared__ int sv[CH];
    __shared__ int sa[CH];
    int t = threadIdx.x;
    hist[t] = 0;
    __syncthreads();
    int base = blockIdx.x * CH;
    int lim = min(E - base, CH);
    int rs[CH / 512], rd[CH / 512];
    #pragma unroll
    for (int k = 0; k < CH / 512; ++k) {
        int i = t + k * 512;
        if (i < lim) {
            rs[k] = ei[base + i];
            rd[k] = ei[E + base + i];
            atomicAdd(&hist[rd[k] >> BSH], 1);
            atomicAdd(&deg[rd[k]], 1);
        }
    }
    __syncthreads();
    int v = hist[t];
    scn[t] = v;
    __syncthreads();
    for (int off = 1; off < 512; off <<= 1) {
        int tmp = (t >= off) ? scn[t - off] : 0;
        __syncthreads();
        scn[t] += tmp;
        __syncthreads();
    }
    int excl = scn[t] - v;
    int g = (v > 0) ? atomicAdd(&gcur[t], v) : 0;
    gdel[t] = t * STRIDE + g - excl;
    hist[t] = excl;
    __syncthreads();
    #pragma unroll
    for (int k = 0; k < CH / 512; ++k) {
        int i = t + k * 512;
        if (i < lim) {
            int s = rs[k];
            int d = rd[k];
            int b = d >> BSH;
            int pos = atomicAdd(&hist[b], 1);
            sv[pos] = ((d & (BSZ - 1)) << SRCBITS) | s;
            sa[pos] = gdel[b] + pos;
        }
    }
    __syncthreads();
    for (int j = t; j < lim; j += 512)
        binned[sa[j]] = sv[j];
}

// Per node: degree -> dinv + fp8 xs row (16 B).
__global__ void k_prep(const int* __restrict__ deg,
                       const float* __restrict__ x, float* __restrict__ dinv,
                       uint4* __restrict__ xs8, int N) {
    int n = blockIdx.x * blockDim.x + threadIdx.x;
    if (n >= N) return;
    float di = rsqrtf((float)deg[n] + 1.0f);   // +1 = self loop
    dinv[n] = di;
    const float4* xv = (const float4*)(x + (size_t)n * PERIODS);
    float4 v0 = xv[0], v1 = xv[1], v2 = xv[2];
    uint4 r;
    r.x = pk4(v0.x * di, v0.y * di, v0.z * di, v0.w * di);
    r.y = pk4(v1.x * di, v1.y * di, v1.z * di, v1.w * di);
    r.z = pk4(v2.x * di, v2.y * di, v2.z * di, v2.w * di);
    r.w = 0;
    xs8[n] = r;
}

// Accumulate one src row into the bucket accumulator, in integer units of
// 2^-9 (exact: fp8 e4m3 values are multiples of 2^-9; *512 is an exact
// integer in f32; v_cvt truncation is therefore exact). ds_add_u32 is
// native HW — no CAS loop, unlike float atomicAdd without unsafe-fp-atomics.
__device__ __forceinline__ void scat(int* acc, int d, uint4 r) {
    float f[PERIODS];
    dec4(r.x, f + 0); dec4(r.y, f + 4); dec4(r.z, f + 8);
    int base = d * ACCS;
    #pragma unroll
    for (int k = 0; k < PERIODS; ++k)
        atomicAdd(&acc[base + k], __float2int_rz(f[k] * 512.f));
}

// Pass 2 (fused): read bucket's binned edges once; gather fp8 src row;
// ds_add_u32 into per-bucket int accumulator; threads 0..255 run the epilogue.
__global__ __launch_bounds__(512) void k_agg(const int* __restrict__ binned,
                                             const int* __restrict__ gcur,
                                             const float* __restrict__ dinv,
                                             const uint4* __restrict__ xs8,
                                             const Consts* __restrict__ C,
                                             const float* __restrict__ out_w,
                                             const float* __restrict__ out_b,
                                             float* __restrict__ out, int N) {
    __shared__ int acc[BSZ * ACCS];
    int b = blockIdx.x, t = threadIdx.x;
    for (int i = t; i < BSZ * ACCS; i += 512) acc[i] = 0;
    __syncthreads();
    int cnt = gcur[b];
    const int* bb = binned + b * STRIDE;
    int i = t;
    for (; i + 1536 < cnt; i += 2048) {      // x4: 4 col loads + 4 gathers in flight
        int p0 = bb[i];
        int p1 = bb[i + 512];
        int p2 = bb[i + 1024];
        int p3 = bb[i + 1536];
        uint4 r0 = xs8[p0 & SMASK];
        uint4 r1 = xs8[p1 & SMASK];
        uint4 r2 = xs8[p2 & SMASK];
        uint4 r3 = xs8[p3 & SMASK];
        scat(acc, p0 >> SRCBITS, r0);
        scat(acc, p1 >> SRCBITS, r1);
        scat(acc, p2 >> SRCBITS, r2);
        scat(acc, p3 >> SRCBITS, r3);
    }
    for (; i < cnt; i += 512) {
        int pv = bb[i];
        uint4 r = xs8[pv & SMASK];
        scat(acc, pv >> SRCBITS, r);
    }
    __syncthreads();

    if (t >= BSZ) return;
    int n = (b << BSH) + t;
    if (n >= N) return;

    float a[PERIODS];
    {   // self term (di-scaled fp8 row) + accumulated neighbors (int -> f32)
        float f[PERIODS];
        uint4 r = xs8[n];
        dec4(r.x, f + 0); dec4(r.y, f + 4); dec4(r.z, f + 8);
        #pragma unroll
        for (int k = 0; k < PERIODS; ++k)
            a[k] = (float)acc[t * ACCS + k] * 0.001953125f + f[k];
    }

    float di = dinv[n];
    float hacc[4] = {0.f, 0.f, 0.f, 0.f};
    #pragma unroll
    for (int p = 0; p < PERIODS; ++p) {
        float ap = di * a[p];
        float pr = C->probs[p];
        #pragma unroll
        for (int c = 0; c < 4; ++c) {
            float zz = 1.f / (1.f + __expf(-(ap * C->az[c] + C->cz[c])));
            float hh = tanhf(ap * C->ah[c] + C->ch[c]);
            hacc[c] += pr * (1.f - zz) * hh;
        }
    }
    float o[PERIODS];
    #pragma unroll
    for (int f = 0; f < PERIODS; ++f) {
        float v = out_b[f];
        #pragma unroll
        for (int c = 0; c < 4; ++c) v += hacc[c] * out_w[c * PERIODS + f];
        o[f] = v;
    }
    float4* ov = (float4*)(out + (size_t)n * PERIODS);
    ov[0] = make_float4(o[0], o[1], o[2],  o[3]);
    ov[1] = make_float4(o[4], o[5], o[6],  o[7]);
    ov[2] = make_float4(o[8], o[9], o[10], o[11]);
}

extern "C" void kernel_launch(void* const* d_in, const int* in_sizes, int n_in,
                              void* d_out, int out_size, void* d_ws, size_t ws_size,
                              hipStream_t stream) {
    const float* x        = (const float*)d_in[0];
    const int*   ei       = (const int*)d_in[1];
    const float* conv_z_w = (const float*)d_in[2];
    const float* conv_z_b = (const float*)d_in[3];
    const float* lin_z_w  = (const float*)d_in[4];
    const float* lin_z_b  = (const float*)d_in[5];
    const float* conv_h_w = (const float*)d_in[10];
    const float* conv_h_b = (const float*)d_in[11];
    const float* lin_h_w  = (const float*)d_in[12];
    const float* lin_h_b  = (const float*)d_in[13];
    const float* att      = (const float*)d_in[14];
    const float* out_w    = (const float*)d_in[15];
    const float* out_b    = (const float*)d_in[16];
    float* out = (float*)d_out;

    const int N  = in_sizes[0] / PERIODS;
    const int E  = in_sizes[1] / 2;
    const int NB = (N + BSZ - 1) / BSZ;          // 391 buckets
    const int gA = (E + CH - 1) / CH;            // binning blocks

    // workspace layout (256B-aligned regions); total ~21 MB
    char* ws = (char*)d_ws;
    size_t off = 0;
    Consts* consts = (Consts*)(ws + off);  off += (sizeof(Consts) + 255) & ~255ull;
    int*    gcur   = (int*)(ws + off);     off += ((size_t)NB * 4 + 255) & ~255ull;
    int*    deg    = (int*)(ws + off);     off += ((size_t)N * 4 + 255) & ~255ull;
    float*  dinv   = (float*)(ws + off);   off += ((size_t)N * 4 + 255) & ~255ull;
    uint4*  xs8    = (uint4*)(ws + off);   off += ((size_t)(N + 256) * 16 + 255) & ~255ull;
    int*    binned = (int*)(ws + off);     off += ((size_t)NB * STRIDE * 4 + 255) & ~255ull;
    (void)ws_size; (void)n_in; (void)out_size;

    k_setup<<<128, 512, 0, stream>>>(conv_z_w, conv_z_b, lin_z_w, lin_z_b,
                                     conv_h_w, conv_h_b, lin_h_w, lin_h_b, att,
                                     consts, gcur, deg, NB, N);
    k_binA<<<gA, 512, 0, stream>>>(ei, gcur, deg, binned, E);
    k_prep<<<(N + 255) / 256, 256, 0, stream>>>(deg, x, dinv, xs8, N);
    k_agg<<<NB, 512, 0, stream>>>(binned, gcur, dinv, xs8, consts,
                                  out_w, out_b, out, N);
}

// Round 4
// 161.295 us; speedup vs baseline: 3.1603x; 1.7290x over previous
//
#include <hip/hip_runtime.h>
#include <hip/hip_fp16.h>
#include <math.h>

// A3TGCN reduced form (H0 == 0 => r-branch dead, GRU collapses):
//   agg[n,p] = dinv[n] * ( sum_{e: dst=n} xs[src[e],p] + xs[n,p] ),  xs = dinv .* x
//   z = sigmoid(agg*az[c]+cz[c]); h = tanh(agg*ah[c]+ch[c])
//   out[n,:] = (sum_p probs[p]*(1-z)*h) @ out_w + out_b
//
// Round 11: identical to round 10 (container infra failed twice; no counter
// evidence against the kernel — resubmitting to measure).
// Round 10: round 9's k_binA was 148 us (vs <=42 in round 7) because the
// folded deg histogram issued 3.2M device-scope global atomics to random
// addresses -> fabric-coherence-point throughput wall. Fix: deg from a
// per-bucket LDS histogram over binned (k_degprep, native ds_add_u32),
// which also absorbs k_prep (dinv + fp8 pack). k_agg halves its LDS atomic
// count with ds_add_u64 packing two period-channels per op; +2^18 bias per
// addend keeps both 32-bit halves carry-isolated (epilogue subtracts
// deg*2^18 exactly). All-integer accumulation -> deterministic.

#define PERIODS 12
#define BSZ     256              // nodes per bucket (2^BSH)
#define BSH     8
#define STRIDE  9216             // bucket capacity: mean 8192 + 11 sigma
#define SRCBITS 17               // N = 100000 < 2^17
#define SMASK   ((1 << SRCBITS) - 1)
#define CH      4096             // edges per k_binA block
#define ACCW    7                // u64 slots per node (6 used + 1 pad)
#define BIAS_I  262144           // 2^18 carry-isolation bias (int units of 2^-9)
#define BIAS_F  262144.f

struct Consts {
    float az[4], cz[4], ah[4], ch[4], probs[PERIODS];
};

// ---------------- fp8 e4m3 helpers (builtin fast path + manual fallback) ----
typedef float vf2 __attribute__((ext_vector_type(2)));

__device__ __forceinline__ float dec1_manual(unsigned b) {
    unsigned e = (b >> 3) & 15u, m = b & 7u;
    float v = e ? __uint_as_float(((e + 120u) << 23) | (m << 20))
                : (float)m * 0.001953125f;          // 2^-9 subnormal step
    return (b & 0x80u) ? -v : v;
}

__device__ __forceinline__ void dec4(unsigned u, float* o) {
#if __has_builtin(__builtin_amdgcn_cvt_pk_f32_fp8)
    vf2 lo = __builtin_amdgcn_cvt_pk_f32_fp8((int)u, false);
    vf2 hi = __builtin_amdgcn_cvt_pk_f32_fp8((int)u, true);
    o[0] = lo.x; o[1] = lo.y; o[2] = hi.x; o[3] = hi.y;
#else
    o[0] = dec1_manual(u & 255u);
    o[1] = dec1_manual((u >> 8) & 255u);
    o[2] = dec1_manual((u >> 16) & 255u);
    o[3] = dec1_manual(u >> 24);
#endif
}

__device__ __forceinline__ unsigned enc1_manual(float x) {
    unsigned s = (__float_as_uint(x) >> 24) & 0x80u;
    float a = fabsf(x);
    if (!(a > 0.f)) return s;
    a = fminf(a, 448.f);
    int eb = (int)(__float_as_uint(a) >> 23) - 127;
    int e = eb < -6 ? -6 : eb;
    float q = rintf(a * exp2f((float)(3 - e)));
    if (q >= 16.f) { e++; q = rintf(a * exp2f((float)(3 - e))); }
    if (e > 8) return s | 0x7Eu;                    // clamp to 448
    int m = (int)q;
    unsigned ee, mm;
    if (m >= 8) { ee = (unsigned)(e + 7); mm = (unsigned)(m - 8); }
    else        { ee = 0u; mm = (unsigned)m; }      // subnormal (e == -6)
    return s | (ee << 3) | mm;
}

__device__ __forceinline__ unsigned pk4(float a, float b, float c, float d) {
#if __has_builtin(__builtin_amdgcn_cvt_pk_fp8_f32)
    int v = __builtin_amdgcn_cvt_pk_fp8_f32(a, b, 0, false);
    v = __builtin_amdgcn_cvt_pk_fp8_f32(c, d, v, true);
    return (unsigned)v;
#else
    return enc1_manual(a) | (enc1_manual(b) << 8) |
           (enc1_manual(c) << 16) | (enc1_manual(d) << 24);
#endif
}

// ---------------------------------------------------------------------------

// Zero gcur; thread 0 folds the constants. Single block (NB small).
__global__ __launch_bounds__(512) void k_setup(const float* conv_z_w, const float* conv_z_b,
                        const float* lin_z_w, const float* lin_z_b,
                        const float* conv_h_w, const float* conv_h_b,
                        const float* lin_h_w, const float* lin_h_b,
                        const float* att, Consts* C, int* gcur, int NB)
{
    int t = threadIdx.x;
    for (int i = t; i < NB; i += 512) gcur[i] = 0;
    if (t == 0) {
        for (int c = 0; c < 4; ++c) {
            float az = 0.f, cz = 0.f, ah = 0.f, ch = 0.f;
            for (int k = 0; k < 4; ++k) {
                az += conv_z_w[k] * lin_z_w[k * 4 + c];
                cz += conv_z_b[k] * lin_z_w[k * 4 + c];
                ah += conv_h_w[k] * lin_h_w[k * 4 + c];
                ch += conv_h_b[k] * lin_h_w[k * 4 + c];
            }
            C->az[c] = az; C->cz[c] = cz + lin_z_b[c];
            C->ah[c] = ah; C->ch[c] = ch + lin_h_b[c];
        }
        float m = att[0];
        for (int p = 1; p < PERIODS; ++p) m = fmaxf(m, att[p]);
        float e[PERIODS]; float s = 0.f;
        for (int p = 0; p < PERIODS; ++p) { e[p] = expf(att[p] - m); s += e[p]; }
        for (int p = 0; p < PERIODS; ++p) C->probs[p] = e[p] / s;
    }
}

// Pass 1: bin edges by dst bucket; register-stage src/dst (edge list read
// once). NO global deg atomics (round-9 lesson: fabric atomic wall).
__global__ __launch_bounds__(512) void k_binA(const int* __restrict__ ei,
                                              int* __restrict__ gcur,
                                              int* __restrict__ binned, int E) {
    __shared__ int hist[512];
    __shared__ int scn[512];
    __shared__ int gdel[512];
    __shared__ int sv[CH];
    __shared__ int sa[CH];
    int t = threadIdx.x;
    hist[t] = 0;
    __syncthreads();
    int base = blockIdx.x * CH;
    int lim = min(E - base, CH);
    int rs[CH / 512], rd[CH / 512];
    #pragma unroll
    for (int k = 0; k < CH / 512; ++k) {
        int i = t + k * 512;
        if (i < lim) {
            rs[k] = ei[base + i];
            rd[k] = ei[E + base + i];
            atomicAdd(&hist[rd[k] >> BSH], 1);
        }
    }
    __syncthreads();
    int v = hist[t];
    scn[t] = v;
    __syncthreads();
    for (int off = 1; off < 512; off <<= 1) {
        int tmp = (t >= off) ? scn[t - off] : 0;
        __syncthreads();
        scn[t] += tmp;
        __syncthreads();
    }
    int excl = scn[t] - v;
    int g = (v > 0) ? atomicAdd(&gcur[t], v) : 0;
    gdel[t] = t * STRIDE + g - excl;
    hist[t] = excl;
    __syncthreads();
    #pragma unroll
    for (int k = 0; k < CH / 512; ++k) {
        int i = t + k * 512;
        if (i < lim) {
            int s = rs[k];
            int d = rd[k];
            int b = d >> BSH;
            int pos = atomicAdd(&hist[b], 1);
            sv[pos] = ((d & (BSZ - 1)) << SRCBITS) | s;
            sa[pos] = gdel[b] + pos;
        }
    }
    __syncthreads();
    for (int j = t; j < lim; j += 512)
        binned[sa[j]] = sv[j];
}

// Per bucket: LDS histogram of dst-in-bucket over this bucket's binned edges
// -> deg/dinv, and pack the bucket's contiguous x slab to fp8 (absorbs the
// old k_prep). Bucket-local ds_add_u32 only — no global atomics.
__global__ __launch_bounds__(512) void k_degprep(const int* __restrict__ binned,
                                                 const int* __restrict__ gcur,
                                                 const float* __restrict__ x,
                                                 int* __restrict__ deg,
                                                 float* __restrict__ dinv,
                                                 uint4* __restrict__ xs8, int N) {
    __shared__ int hist[BSZ];
    int b = blockIdx.x, t = threadIdx.x;
    if (t < BSZ) hist[t] = 0;
    __syncthreads();
    int cnt = gcur[b];
    const int* bb = binned + b * STRIDE;
    for (int i = t; i < cnt; i += 512)
        atomicAdd(&hist[bb[i] >> SRCBITS], 1);
    __syncthreads();
    if (t >= BSZ) return;
    int n = (b << BSH) + t;
    if (n >= N) return;
    int dg = hist[t];
    deg[n] = dg;
    float di = rsqrtf((float)dg + 1.0f);   // +1 = self loop
    dinv[n] = di;
    const float4* xv = (const float4*)(x + (size_t)n * PERIODS);
    float4 v0 = xv[0], v1 = xv[1], v2 = xv[2];
    uint4 r;
    r.x = pk4(v0.x * di, v0.y * di, v0.z * di, v0.w * di);
    r.y = pk4(v1.x * di, v1.y * di, v1.z * di, v1.w * di);
    r.z = pk4(v2.x * di, v2.y * di, v2.z * di, v2.w * di);
    r.w = 0;
    xs8[n] = r;
}

// Accumulate one src row: integer units of 2^-9 (exact for fp8 e4m3), two
// period-channels per native ds_add_u64. +BIAS per addend keeps both 32-bit
// halves positive so no carry crosses bit 31 (sums < deg*(2^18+229376) << 2^31);
// epilogue subtracts deg*BIAS exactly.
__device__ __forceinline__ void scat(unsigned long long* acc, int d, uint4 r) {
    float f[PERIODS];
    dec4(r.x, f + 0); dec4(r.y, f + 4); dec4(r.z, f + 8);
    int base = d * ACCW;
    #pragma unroll
    for (int k = 0; k < 6; ++k) {
        unsigned lo = (unsigned)__float2int_rn(fmaf(f[k],     512.f, BIAS_F));
        unsigned hi = (unsigned)__float2int_rn(fmaf(f[k + 6], 512.f, BIAS_F));
        atomicAdd(&acc[base + k], ((unsigned long long)hi << 32) | (unsigned long long)lo);
    }
}

// Pass 2 (fused): read bucket's binned edges once; gather fp8 src row;
// ds_add_u64 into per-bucket accumulator; threads 0..255 run the epilogue.
__global__ __launch_bounds__(512) void k_agg(const int* __restrict__ binned,
                                             const int* __restrict__ gcur,
                                             const int* __restrict__ deg,
                                             const float* __restrict__ dinv,
                                             const uint4* __restrict__ xs8,
                                             const Consts* __restrict__ C,
                                             const float* __restrict__ out_w,
                                             const float* __restrict__ out_b,
                                             float* __restrict__ out, int N) {
    __shared__ unsigned long long acc[BSZ * ACCW];
    int b = blockIdx.x, t = threadIdx.x;
    for (int i = t; i < BSZ * ACCW; i += 512) acc[i] = 0ull;
    __syncthreads();
    int cnt = gcur[b];
    const int* bb = binned + b * STRIDE;
    int i = t;
    for (; i + 1536 < cnt; i += 2048) {      // x4: 4 col loads + 4 gathers in flight
        int p0 = bb[i];
        int p1 = bb[i + 512];
        int p2 = bb[i + 1024];
        int p3 = bb[i + 1536];
        uint4 r0 = xs8[p0 & SMASK];
        uint4 r1 = xs8[p1 & SMASK];
        uint4 r2 = xs8[p2 & SMASK];
        uint4 r3 = xs8[p3 & SMASK];
        scat(acc, p0 >> SRCBITS, r0);
        scat(acc, p1 >> SRCBITS, r1);
        scat(acc, p2 >> SRCBITS, r2);
        scat(acc, p3 >> SRCBITS, r3);
    }
    for (; i < cnt; i += 512) {
        int pv = bb[i];
        uint4 r = xs8[pv & SMASK];
        scat(acc, pv >> SRCBITS, r);
    }
    __syncthreads();

    if (t >= BSZ) return;
    int n = (b << BSH) + t;
    if (n >= N) return;

    int corr = deg[n] << 18;                 // deg * BIAS (exact)
    float a[PERIODS];
    {   // self term (di-scaled fp8 row) + accumulated neighbors (int -> f32)
        float f[PERIODS];
        uint4 r = xs8[n];
        dec4(r.x, f + 0); dec4(r.y, f + 4); dec4(r.z, f + 8);
        #pragma unroll
        for (int k = 0; k < 6; ++k) {
            unsigned long long u = acc[t * ACCW + k];
            int lo = (int)(unsigned)(u & 0xFFFFFFFFull) - corr;
            int hi = (int)(unsigned)(u >> 32) - corr;
            a[k]     = (float)lo * 0.001953125f + f[k];
            a[k + 6] = (float)hi * 0.001953125f + f[k + 6];
        }
    }

    float di = dinv[n];
    float hacc[4] = {0.f, 0.f, 0.f, 0.f};
    #pragma unroll
    for (int p = 0; p < PERIODS; ++p) {
        float ap = di * a[p];
        float pr = C->probs[p];
        #pragma unroll
        for (int c = 0; c < 4; ++c) {
            float zz = 1.f / (1.f + __expf(-(ap * C->az[c] + C->cz[c])));
            float hh = tanhf(ap * C->ah[c] + C->ch[c]);
            hacc[c] += pr * (1.f - zz) * hh;
        }
    }
    float o[PERIODS];
    #pragma unroll
    for (int f = 0; f < PERIODS; ++f) {
        float v = out_b[f];
        #pragma unroll
        for (int c = 0; c < 4; ++c) v += hacc[c] * out_w[c * PERIODS + f];
        o[f] = v;
    }
    float4* ov = (float4*)(out + (size_t)n * PERIODS);
    ov[0] = make_float4(o[0], o[1], o[2],  o[3]);
    ov[1] = make_float4(o[4], o[5], o[6],  o[7]);
    ov[2] = make_float4(o[8], o[9], o[10], o[11]);
}

extern "C" void kernel_launch(void* const* d_in, const int* in_sizes, int n_in,
                              void* d_out, int out_size, void* d_ws, size_t ws_size,
                              hipStream_t stream) {
    const float* x        = (const float*)d_in[0];
    const int*   ei       = (const int*)d_in[1];
    const float* conv_z_w = (const float*)d_in[2];
    const float* conv_z_b = (const float*)d_in[3];
    const float* lin_z_w  = (const float*)d_in[4];
    const float* lin_z_b  = (const float*)d_in[5];
    const float* conv_h_w = (const float*)d_in[10];
    const float* conv_h_b = (const float*)d_in[11];
    const float* lin_h_w  = (const float*)d_in[12];
    const float* lin_h_b  = (const float*)d_in[13];
    const float* att      = (const float*)d_in[14];
    const float* out_w    = (const float*)d_in[15];
    const float* out_b    = (const float*)d_in[16];
    float* out = (float*)d_out;

    const int N  = in_sizes[0] / PERIODS;
    const int E  = in_sizes[1] / 2;
    const int NB = (N + BSZ - 1) / BSZ;          // 391 buckets
    const int gA = (E + CH - 1) / CH;            // binning blocks

    // workspace layout (256B-aligned regions); total ~21 MB
    char* ws = (char*)d_ws;
    size_t off = 0;
    Consts* consts = (Consts*)(ws + off);  off += (sizeof(Consts) + 255) & ~255ull;
    int*    gcur   = (int*)(ws + off);     off += ((size_t)NB * 4 + 255) & ~255ull;
    int*    deg    = (int*)(ws + off);     off += ((size_t)N * 4 + 255) & ~255ull;
    float*  dinv   = (float*)(ws + off);   off += ((size_t)N * 4 + 255) & ~255ull;
    uint4*  xs8    = (uint4*)(ws + off);   off += ((size_t)(N + 256) * 16 + 255) & ~255ull;
    int*    binned = (int*)(ws + off);     off += ((size_t)NB * STRIDE * 4 + 255) & ~255ull;
    (void)ws_size; (void)n_in; (void)out_size;

    k_setup<<<1, 512, 0, stream>>>(conv_z_w, conv_z_b, lin_z_w, lin_z_b,
                                   conv_h_w, conv_h_b, lin_h_w, lin_h_b, att,
                                   consts, gcur, NB);
    k_binA<<<gA, 512, 0, stream>>>(ei, gcur, binned, E);
    k_degprep<<<NB, 512, 0, stream>>>(binned, gcur, x, deg, dinv, xs8, N);
    k_agg<<<NB, 512, 0, stream>>>(binned, gcur, deg, dinv, xs8, consts,
                                  out_w, out_b, out, N);
}

// Round 5
// 160.041 us; speedup vs baseline: 3.1850x; 1.0078x over previous
//
#include <hip/hip_runtime.h>
#include <hip/hip_fp16.h>
#include <math.h>

// A3TGCN reduced form (H0 == 0 => r-branch dead, GRU collapses):
//   agg[n,p] = dinv[n] * ( sum_{e: dst=n} xs[src[e],p] + xs[n,p] ),  xs = dinv .* x
//   z = sigmoid(agg*az[c]+cz[c]); h = tanh(agg*ah[c]+ch[c])
//   out[n,:] = (sum_p probs[p]*(1-z)*h) @ out_w + out_b
//
// Round 12: occupancy round. rocprof r4: k_agg 53us @ Occupancy 21%,
// VALUBusy 13.7%, HBM 4% -> latency-bound at starvation occupancy (391
// blocks x 8 waves = 12 waves/CU). Fix: 1024-thread blocks (16 waves) for
// k_agg/k_degprep -> ~24 waves/CU. k_binA was write-amp bound (round-2
// counters: WRITE_SIZE 119MB for 12.8MB logical; ~10-edge runs dirty whole
// lines): 1024 threads + CH=8192 doubles run length (~21 edges) to halve
// amplification. Accumulation math unchanged (int units of 2^-9,
// ds_add_u64 2-channel packing, +2^18 carry-isolation bias).

#define PERIODS 12
#define BSZ     256              // nodes per bucket (2^BSH)
#define BSH     8
#define STRIDE  9216             // bucket capacity: mean 8192 + 11 sigma
#define SRCBITS 17               // N = 100000 < 2^17
#define SMASK   ((1 << SRCBITS) - 1)
#define CH      8192             // edges per k_binA block
#define NT      1024             // threads per block (heavy kernels)
#define ACCW    7                // u64 slots per node (6 used + 1 pad)
#define BIAS_F  262144.f         // 2^18 carry-isolation bias (units of 2^-9)

struct Consts {
    float az[4], cz[4], ah[4], ch[4], probs[PERIODS];
};

// ---------------- fp8 e4m3 helpers (builtin fast path + manual fallback) ----
typedef float vf2 __attribute__((ext_vector_type(2)));

__device__ __forceinline__ float dec1_manual(unsigned b) {
    unsigned e = (b >> 3) & 15u, m = b & 7u;
    float v = e ? __uint_as_float(((e + 120u) << 23) | (m << 20))
                : (float)m * 0.001953125f;          // 2^-9 subnormal step
    return (b & 0x80u) ? -v : v;
}

__device__ __forceinline__ void dec4(unsigned u, float* o) {
#if __has_builtin(__builtin_amdgcn_cvt_pk_f32_fp8)
    vf2 lo = __builtin_amdgcn_cvt_pk_f32_fp8((int)u, false);
    vf2 hi = __builtin_amdgcn_cvt_pk_f32_fp8((int)u, true);
    o[0] = lo.x; o[1] = lo.y; o[2] = hi.x; o[3] = hi.y;
#else
    o[0] = dec1_manual(u & 255u);
    o[1] = dec1_manual((u >> 8) & 255u);
    o[2] = dec1_manual((u >> 16) & 255u);
    o[3] = dec1_manual(u >> 24);
#endif
}

__device__ __forceinline__ unsigned enc1_manual(float x) {
    unsigned s = (__float_as_uint(x) >> 24) & 0x80u;
    float a = fabsf(x);
    if (!(a > 0.f)) return s;
    a = fminf(a, 448.f);
    int eb = (int)(__float_as_uint(a) >> 23) - 127;
    int e = eb < -6 ? -6 : eb;
    float q = rintf(a * exp2f((float)(3 - e)));
    if (q >= 16.f) { e++; q = rintf(a * exp2f((float)(3 - e))); }
    if (e > 8) return s | 0x7Eu;                    // clamp to 448
    int m = (int)q;
    unsigned ee, mm;
    if (m >= 8) { ee = (unsigned)(e + 7); mm = (unsigned)(m - 8); }
    else        { ee = 0u; mm = (unsigned)m; }      // subnormal (e == -6)
    return s | (ee << 3) | mm;
}

__device__ __forceinline__ unsigned pk4(float a, float b, float c, float d) {
#if __has_builtin(__builtin_amdgcn_cvt_pk_fp8_f32)
    int v = __builtin_amdgcn_cvt_pk_fp8_f32(a, b, 0, false);
    v = __builtin_amdgcn_cvt_pk_fp8_f32(c, d, v, true);
    return (unsigned)v;
#else
    return enc1_manual(a) | (enc1_manual(b) << 8) |
           (enc1_manual(c) << 16) | (enc1_manual(d) << 24);
#endif
}

// ---------------------------------------------------------------------------

// Zero gcur; thread 0 folds the constants. Single block (NB small).
__global__ __launch_bounds__(512) void k_setup(const float* conv_z_w, const float* conv_z_b,
                        const float* lin_z_w, const float* lin_z_b,
                        const float* conv_h_w, const float* conv_h_b,
                        const float* lin_h_w, const float* lin_h_b,
                        const float* att, Consts* C, int* gcur, int NB)
{
    int t = threadIdx.x;
    for (int i = t; i < NB; i += 512) gcur[i] = 0;
    if (t == 0) {
        for (int c = 0; c < 4; ++c) {
            float az = 0.f, cz = 0.f, ah = 0.f, ch = 0.f;
            for (int k = 0; k < 4; ++k) {
                az += conv_z_w[k] * lin_z_w[k * 4 + c];
                cz += conv_z_b[k] * lin_z_w[k * 4 + c];
                ah += conv_h_w[k] * lin_h_w[k * 4 + c];
                ch += conv_h_b[k] * lin_h_w[k * 4 + c];
            }
            C->az[c] = az; C->cz[c] = cz + lin_z_b[c];
            C->ah[c] = ah; C->ch[c] = ch + lin_h_b[c];
        }
        float m = att[0];
        for (int p = 1; p < PERIODS; ++p) m = fmaxf(m, att[p]);
        float e[PERIODS]; float s = 0.f;
        for (int p = 0; p < PERIODS; ++p) { e[p] = expf(att[p] - m); s += e[p]; }
        for (int p = 0; p < PERIODS; ++p) C->probs[p] = e[p] / s;
    }
}

// Pass 1: bin edges by dst bucket. CH=8192 @ 1024 threads: longer per-bucket
// runs (~21 edges) halve the scatter write amplification. sv+sa = 64 KB LDS.
__global__ __launch_bounds__(NT, 4) void k_binA(const int* __restrict__ ei,
                                                int* __restrict__ gcur,
                                                int* __restrict__ binned, int E) {
    __shared__ int hist[512];
    __shared__ int scn[512];
    __shared__ int gdel[512];
    __shared__ int sv[CH];
    __shared__ int sa[CH];
    int t = threadIdx.x;
    if (t < 512) hist[t] = 0;
    __syncthreads();
    int base = blockIdx.x * CH;
    int lim = min(E - base, CH);
    int rs[CH / NT], rd[CH / NT];
    #pragma unroll
    for (int k = 0; k < CH / NT; ++k) {
        int i = t + k * NT;
        if (i < lim) {
            rs[k] = ei[base + i];
            rd[k] = ei[E + base + i];
            atomicAdd(&hist[rd[k] >> BSH], 1);
        }
    }
    __syncthreads();
    int v = 0;
    if (t < 512) { v = hist[t]; scn[t] = v; }
    __syncthreads();
    for (int off = 1; off < 512; off <<= 1) {
        int tmp = 0;
        if (t < 512 && t >= off) tmp = scn[t - off];
        __syncthreads();
        if (t < 512) scn[t] += tmp;
        __syncthreads();
    }
    if (t < 512) {
        int excl = scn[t] - v;
        int g = (v > 0) ? atomicAdd(&gcur[t], v) : 0;
        gdel[t] = t * STRIDE + g - excl;
        hist[t] = excl;
    }
    __syncthreads();
    #pragma unroll
    for (int k = 0; k < CH / NT; ++k) {
        int i = t + k * NT;
        if (i < lim) {
            int s = rs[k];
            int d = rd[k];
            int b = d >> BSH;
            int pos = atomicAdd(&hist[b], 1);
            sv[pos] = ((d & (BSZ - 1)) << SRCBITS) | s;
            sa[pos] = gdel[b] + pos;
        }
    }
    __syncthreads();
    for (int j = t; j < lim; j += NT)
        binned[sa[j]] = sv[j];
}

// Per bucket: LDS histogram of dst-in-bucket over this bucket's binned edges
// -> deg/dinv, and pack the bucket's contiguous x slab to fp8.
__global__ __launch_bounds__(NT, 4) void k_degprep(const int* __restrict__ binned,
                                                   const int* __restrict__ gcur,
                                                   const float* __restrict__ x,
                                                   int* __restrict__ deg,
                                                   float* __restrict__ dinv,
                                                   uint4* __restrict__ xs8, int N) {
    __shared__ int hist[BSZ];
    int b = blockIdx.x, t = threadIdx.x;
    if (t < BSZ) hist[t] = 0;
    __syncthreads();
    int cnt = gcur[b];
    const int* bb = binned + b * STRIDE;
    for (int i = t; i < cnt; i += NT)
        atomicAdd(&hist[bb[i] >> SRCBITS], 1);
    __syncthreads();
    if (t >= BSZ) return;
    int n = (b << BSH) + t;
    if (n >= N) return;
    int dg = hist[t];
    deg[n] = dg;
    float di = rsqrtf((float)dg + 1.0f);   // +1 = self loop
    dinv[n] = di;
    const float4* xv = (const float4*)(x + (size_t)n * PERIODS);
    float4 v0 = xv[0], v1 = xv[1], v2 = xv[2];
    uint4 r;
    r.x = pk4(v0.x * di, v0.y * di, v0.z * di, v0.w * di);
    r.y = pk4(v1.x * di, v1.y * di, v1.z * di, v1.w * di);
    r.z = pk4(v2.x * di, v2.y * di, v2.z * di, v2.w * di);
    r.w = 0;
    xs8[n] = r;
}

// Accumulate one src row: integer units of 2^-9 (exact for fp8 e4m3), two
// period-channels per native ds_add_u64. +BIAS per addend keeps both 32-bit
// halves positive so no carry crosses bit 31 (sums < deg*(2^18+229376) << 2^31);
// epilogue subtracts deg*BIAS exactly.
__device__ __forceinline__ void scat(unsigned long long* acc, int d, uint4 r) {
    float f[PERIODS];
    dec4(r.x, f + 0); dec4(r.y, f + 4); dec4(r.z, f + 8);
    int base = d * ACCW;
    #pragma unroll
    for (int k = 0; k < 6; ++k) {
        unsigned lo = (unsigned)__float2int_rn(fmaf(f[k],     512.f, BIAS_F));
        unsigned hi = (unsigned)__float2int_rn(fmaf(f[k + 6], 512.f, BIAS_F));
        atomicAdd(&acc[base + k], ((unsigned long long)hi << 32) | (unsigned long long)lo);
    }
}

// Pass 2 (fused): read bucket's binned edges once; gather fp8 src row;
// ds_add_u64 into per-bucket accumulator; threads 0..255 run the epilogue.
__global__ __launch_bounds__(NT, 4) void k_agg(const int* __restrict__ binned,
                                               const int* __restrict__ gcur,
                                               const int* __restrict__ deg,
                                               const float* __restrict__ dinv,
                                               const uint4* __restrict__ xs8,
                                               const Consts* __restrict__ C,
                                               const float* __restrict__ out_w,
                                               const float* __restrict__ out_b,
                                               float* __restrict__ out, int N) {
    __shared__ unsigned long long acc[BSZ * ACCW];
    int b = blockIdx.x, t = threadIdx.x;
    for (int i = t; i < BSZ * ACCW; i += NT) acc[i] = 0ull;
    __syncthreads();
    int cnt = gcur[b];
    const int* bb = binned + b * STRIDE;
    int i = t;
    for (; i + 3 * NT < cnt; i += 4 * NT) {  // x4: 4 col loads + 4 gathers in flight
        int p0 = bb[i];
        int p1 = bb[i + NT];
        int p2 = bb[i + 2 * NT];
        int p3 = bb[i + 3 * NT];
        uint4 r0 = xs8[p0 & SMASK];
        uint4 r1 = xs8[p1 & SMASK];
        uint4 r2 = xs8[p2 & SMASK];
        uint4 r3 = xs8[p3 & SMASK];
        scat(acc, p0 >> SRCBITS, r0);
        scat(acc, p1 >> SRCBITS, r1);
        scat(acc, p2 >> SRCBITS, r2);
        scat(acc, p3 >> SRCBITS, r3);
    }
    for (; i < cnt; i += NT) {
        int pv = bb[i];
        uint4 r = xs8[pv & SMASK];
        scat(acc, pv >> SRCBITS, r);
    }
    __syncthreads();

    if (t >= BSZ) return;
    int n = (b << BSH) + t;
    if (n >= N) return;

    int corr = deg[n] << 18;                 // deg * BIAS (exact)
    float a[PERIODS];
    {   // self term (di-scaled fp8 row) + accumulated neighbors (int -> f32)
        float f[PERIODS];
        uint4 r = xs8[n];
        dec4(r.x, f + 0); dec4(r.y, f + 4); dec4(r.z, f + 8);
        #pragma unroll
        for (int k = 0; k < 6; ++k) {
            unsigned long long u = acc[t * ACCW + k];
            int lo = (int)(unsigned)(u & 0xFFFFFFFFull) - corr;
            int hi = (int)(unsigned)(u >> 32) - corr;
            a[k]     = (float)lo * 0.001953125f + f[k];
            a[k + 6] = (float)hi * 0.001953125f + f[k + 6];
        }
    }

    float di = dinv[n];
    float hacc[4] = {0.f, 0.f, 0.f, 0.f};
    #pragma unroll
    for (int p = 0; p < PERIODS; ++p) {
        float ap = di * a[p];
        float pr = C->probs[p];
        #pragma unroll
        for (int c = 0; c < 4; ++c) {
            float zz = 1.f / (1.f + __expf(-(ap * C->az[c] + C->cz[c])));
            float hh = tanhf(ap * C->ah[c] + C->ch[c]);
            hacc[c] += pr * (1.f - zz) * hh;
        }
    }
    float o[PERIODS];
    #pragma unroll
    for (int f = 0; f < PERIODS; ++f) {
        float v = out_b[f];
        #pragma unroll
        for (int c = 0; c < 4; ++c) v += hacc[c] * out_w[c * PERIODS + f];
        o[f] = v;
    }
    float4* ov = (float4*)(out + (size_t)n * PERIODS);
    ov[0] = make_float4(o[0], o[1], o[2],  o[3]);
    ov[1] = make_float4(o[4], o[5], o[6],  o[7]);
    ov[2] = make_float4(o[8], o[9], o[10], o[11]);
}

extern "C" void kernel_launch(void* const* d_in, const int* in_sizes, int n_in,
                              void* d_out, int out_size, void* d_ws, size_t ws_size,
                              hipStream_t stream) {
    const float* x        = (const float*)d_in[0];
    const int*   ei       = (const int*)d_in[1];
    const float* conv_z_w = (const float*)d_in[2];
    const float* conv_z_b = (const float*)d_in[3];
    const float* lin_z_w  = (const float*)d_in[4];
    const float* lin_z_b  = (const float*)d_in[5];
    const float* conv_h_w = (const float*)d_in[10];
    const float* conv_h_b = (const float*)d_in[11];
    const float* lin_h_w  = (const float*)d_in[12];
    const float* lin_h_b  = (const float*)d_in[13];
    const float* att      = (const float*)d_in[14];
    const float* out_w    = (const float*)d_in[15];
    const float* out_b    = (const float*)d_in[16];
    float* out = (float*)d_out;

    const int N  = in_sizes[0] / PERIODS;
    const int E  = in_sizes[1] / 2;
    const int NB = (N + BSZ - 1) / BSZ;          // 391 buckets
    const int gA = (E + CH - 1) / CH;            // binning blocks

    // workspace layout (256B-aligned regions); total ~21 MB
    char* ws = (char*)d_ws;
    size_t off = 0;
    Consts* consts = (Consts*)(ws + off);  off += (sizeof(Consts) + 255) & ~255ull;
    int*    gcur   = (int*)(ws + off);     off += ((size_t)NB * 4 + 255) & ~255ull;
    int*    deg    = (int*)(ws + off);     off += ((size_t)N * 4 + 255) & ~255ull;
    float*  dinv   = (float*)(ws + off);   off += ((size_t)N * 4 + 255) & ~255ull;
    uint4*  xs8    = (uint4*)(ws + off);   off += ((size_t)(N + 256) * 16 + 255) & ~255ull;
    int*    binned = (int*)(ws + off);     off += ((size_t)NB * STRIDE * 4 + 255) & ~255ull;
    (void)ws_size; (void)n_in; (void)out_size;

    k_setup<<<1, 512, 0, stream>>>(conv_z_w, conv_z_b, lin_z_w, lin_z_b,
                                   conv_h_w, conv_h_b, lin_h_w, lin_h_b, att,
                                   consts, gcur, NB);
    k_binA<<<gA, NT, 0, stream>>>(ei, gcur, binned, E);
    k_degprep<<<NB, NT, 0, stream>>>(binned, gcur, x, deg, dinv, xs8, N);
    k_agg<<<NB, NT, 0, stream>>>(binned, gcur, deg, dinv, xs8, consts,
                                 out_w, out_b, out, N);
}